// Round 9
// baseline (189.042 us; speedup 1.0000x reference)
//
#include <hip/hip_runtime.h>
#include <hip/hip_bf16.h>

// Problem constants (B=4, S=2048 -> 8192 tokens; D=O=1024; E=8; top-2)
#define NTOK 8192
#define DDIM 1024
#define ODIM 1024
#define NEXP 8
#define BK   32
#define NKT  (DDIM / BK)     // 32 K-tiles

typedef __attribute__((ext_vector_type(8))) short short8;
typedef __attribute__((ext_vector_type(4))) float f32x4;

// ---- workspace layout (bytes) ----
#define CNT_OFF   0u                               // 16 ints (expert x rank)
#define SC_OFF    (4u * 1024u)                     // 8192*2 floats
#define LIST_OFF  (128u * 1024u)                   // 16*8192 ints = 512 KiB
#define XH_OFF    (1u << 20)                       // bf16 x, 16 MiB
#define WH_OFF    ((1u << 20) + 16u*1024u*1024u)   // bf16 W, 16 MiB
#define O2_OFF    ((1u << 20) + 32u*1024u*1024u)   // rank-1 accum, 32 MiB
#define WS_NEED   ((size_t)O2_OFF + (size_t)NTOK * ODIM * 4u)

__device__ inline unsigned short f2bf(float f) {
    unsigned int u = __float_as_uint(f);
    unsigned int r = (u + 0x7FFFu + ((u >> 16) & 1u)) >> 16;   // RNE
    return (unsigned short)r;
}

__device__ inline void glds16(const unsigned short* g, unsigned short* l) {
    __builtin_amdgcn_global_load_lds(
        (const __attribute__((address_space(1))) unsigned int*)g,
        (__attribute__((address_space(3))) unsigned int*)l, 16, 0, 0);
}

// W fp32->bf16; block 0 also zeroes the 16 expert-x-rank counts (pre-gate)
__global__ void k_cvtw(const float4* __restrict__ src, ushort4* __restrict__ dst,
                       int n4, int* __restrict__ counts) {
    if (blockIdx.x == 0 && threadIdx.x < 16) counts[threadIdx.x] = 0;
    int i = blockIdx.x * blockDim.x + threadIdx.x;
    if (i >= n4) return;
    float4 v = src[i];
    ushort4 o;
    o.x = f2bf(v.x); o.y = f2bf(v.y); o.z = f2bf(v.z); o.w = f2bf(v.w);
    dst[i] = o;
}

// Gating: 1024 blocks x 8 tokens (2 per wave). No VGPR clamp (round 5 spill
// lesson). fp64 dot+butterfly decides top-k; fp32 expf weights. 16 lists
// (expert x rank), block-aggregated scatter. Fused bf16 conversion of x.
// Bias is folded into the GEMM epilogue (no out init here).
__global__ __launch_bounds__(256) void k_gate(
    const float* __restrict__ x, const float* __restrict__ Wg,
    const float* __restrict__ bg, float* __restrict__ scores2,
    int* __restrict__ lists, int* __restrict__ counts,
    unsigned short* __restrict__ xh)
{
    __shared__ unsigned char s_eid[16];     // 8 tokens * 2 entries
    const int tid = threadIdx.x, wave = tid >> 6, lane = tid & 63;
    const int tblk = blockIdx.x * 8;

    #pragma unroll 1
    for (int ti = 0; ti < 2; ti++) {
        const int t = tblk + wave * 2 + ti;
        const float* xr = x + (size_t)t * DDIM;
        float4 xv[4];
        #pragma unroll
        for (int i = 0; i < 4; i++)
            xv[i] = *(const float4*)&xr[lane * 4 + 256 * i];

        unsigned short* xhr = xh + (size_t)t * DDIM;
        #pragma unroll
        for (int i = 0; i < 4; i++) {
            ushort4 h;
            h.x = f2bf(xv[i].x); h.y = f2bf(xv[i].y);
            h.z = f2bf(xv[i].z); h.w = f2bf(xv[i].w);
            *(ushort4*)&xhr[lane * 4 + 256 * i] = h;
        }

        double lg[NEXP];
        #pragma unroll
        for (int e = 0; e < NEXP; e++) {
            const float* wr = Wg + (size_t)e * DDIM;
            double a = 0.0;
            #pragma unroll
            for (int i = 0; i < 4; i++) {
                float4 wv = *(const float4*)&wr[lane * 4 + 256 * i];
                a += (double)xv[i].x * (double)wv.x + (double)xv[i].y * (double)wv.y
                   + (double)xv[i].z * (double)wv.z + (double)xv[i].w * (double)wv.w;
            }
            #pragma unroll
            for (int off = 32; off > 0; off >>= 1) a += __shfl_xor(a, off);
            lg[e] = a + (double)bg[e];
        }

        int i0 = -1, i1 = -1;
        double best = -1e300, sec = -1e300;
        #pragma unroll
        for (int e = 0; e < NEXP; e++) {
            double v = lg[e];
            if (v > best) { sec = best; i1 = i0; best = v; i0 = e; }
            else if (v > sec) { sec = v; i1 = e; }
        }
        float sum = 0.f;
        #pragma unroll
        for (int e = 0; e < NEXP; e++) sum += expf((float)(lg[e] - best));
        float s0 = 1.f / sum;
        float s1 = expf((float)(sec - best)) / sum;

        if (lane == 0) {
            scores2[t * 2 + 0] = s0;
            scores2[t * 2 + 1] = s1;
            int le = (wave * 2 + ti) * 2;
            s_eid[le + 0] = (unsigned char)i0;
            s_eid[le + 1] = (unsigned char)i1;
        }
    }
    __syncthreads();

    // 16 owners: e = tid&7, rank = tid>>3; one global atomic per (block,owner)
    if (tid < 16) {
        int e = tid & 7, kk = tid >> 3;
        int c = 0;
        #pragma unroll
        for (int j = 0; j < 8; j++) c += (s_eid[j * 2 + kk] == e);
        if (c) {
            int p = atomicAdd(&counts[tid], c);
            #pragma unroll
            for (int j = 0; j < 8; j++)
                if (s_eid[j * 2 + kk] == e)
                    lists[tid * NTOK + (p++)] = (tblk + j) * 2 + kk;
        }
    }
}

// Grouped GEMM over 16 (expert x rank) lists, BLOCK-PER-TILE.
// Tile 128x256 (BM=128 token rows, BN=256 output cols): A-traffic halves vs
// 128x128 (4 n-tiles/row instead of 8) -> panel traffic 528->400 MB; n-tiles
// of one m-panel are consecutive in the XCD chunk so A rows + the expert's
// 2MB W panel stay L2-hot. 4 waves; wave w owns cols [w*64,w*64+64), all 128
// rows -> acc[8][4]. BK=32 double-buffered (48 KiB LDS), one __syncthreads
// per K-step, XOR seg-swizzle (0 conflicts, verified). Epilogue pure-store
// with bias folded: out_row = s*(acc + b[e]); rank-0 -> out, rank-1 -> out2.
__global__ __launch_bounds__(256) void k_gemm(
    const unsigned short* __restrict__ xh, const unsigned short* __restrict__ wh,
    const int* __restrict__ counts, const int* __restrict__ lists,
    const float* __restrict__ scores2, const float* __restrict__ bias,
    float* __restrict__ out, float* __restrict__ out2, int listLo, int listHi)
{
    __shared__ __align__(16) unsigned short As[2][128 * BK];   // 16 KiB
    __shared__ __align__(16) unsigned short Bs[2][256 * BK];   // 32 KiB

    // bijective chunked XCD swizzle (gridDim % 8 == 0)
    const int nwg = (int)gridDim.x;
    int bid = ((int)blockIdx.x & 7) * (nwg >> 3) + ((int)blockIdx.x >> 3);

    int li = -1, mt = 0, nt = 0, cnt = 0;
    #pragma unroll
    for (int i = 0; i < 16; i++) {
        if (i < listLo || i >= listHi) continue;
        int c = counts[i];
        int tiles = ((c + 127) >> 7) * 4;      // 4 n-tiles (BN=256)
        if (li < 0) {
            if (bid < tiles) { li = i; mt = bid >> 2; nt = bid & 3; cnt = c; }
            else bid -= tiles;
        }
    }
    if (li < 0) return;

    const int m0 = mt * 128, n0 = nt * 256;
    const int* list = lists + li * NTOK;
    const int exp_ = li & 7;
    const unsigned short* whE = wh + (size_t)exp_ * ODIM * DDIM;
    const int tid = threadIdx.x, wid = tid >> 6, lane = tid & 63;

    // staging: 64 rows per call (16 rows/wave, lane -> row=lane>>2, seg=lane&3)
    const int rl = lane >> 2, slx = lane & 3;
    const unsigned short* aS[2];
    const unsigned short* bS[4];
    int rbA[2], rbB[4];
    #pragma unroll
    for (int i = 0; i < 2; i++) {
        int R = i * 64 + wid * 16 + rl;                 // 0..127
        int sl = slx ^ ((R >> 1) & 3);
        int g = m0 + R; if (g >= cnt) g = cnt - 1;
        aS[i] = xh + (size_t)(list[g] >> 1) * DDIM + sl * 8;
        rbA[i] = (i * 64 + wid * 16) * BK;
    }
    #pragma unroll
    for (int c = 0; c < 4; c++) {
        int R = c * 64 + wid * 16 + rl;                 // 0..255
        int sl = slx ^ ((R >> 1) & 3);
        bS[c] = whE + (size_t)(n0 + R) * DDIM + sl * 8;
        rbB[c] = (c * 64 + wid * 16) * BK;
    }

    const int fr = lane & 15, g4 = lane >> 4;
    const int ph = g4 ^ ((fr >> 1) & 3);                // swizzled seg for reads

    f32x4 acc[8][4];
    #pragma unroll
    for (int m = 0; m < 8; m++)
        #pragma unroll
        for (int n = 0; n < 4; n++)
            acc[m][n] = (f32x4){0.f, 0.f, 0.f, 0.f};

    #pragma unroll
    for (int i = 0; i < 2; i++) glds16(aS[i], &As[0][rbA[i]]);
    #pragma unroll
    for (int c = 0; c < 4; c++) glds16(bS[c], &Bs[0][rbB[c]]);

    int buf = 0;
    #pragma unroll 1
    for (int t = 0; t < NKT; t++) {
        __syncthreads();                 // stage(t) landed (vmcnt drain)
        if (t + 1 < NKT) {
            const int k0 = (t + 1) * BK;
            #pragma unroll
            for (int i = 0; i < 2; i++) glds16(aS[i] + k0, &As[buf ^ 1][rbA[i]]);
            #pragma unroll
            for (int c = 0; c < 4; c++) glds16(bS[c] + k0, &Bs[buf ^ 1][rbB[c]]);
        }
        short8 af[8], bf_[4];
        #pragma unroll
        for (int m = 0; m < 8; m++)
            af[m] = *(const short8*)&As[buf][(m * 16 + fr) * BK + ph * 8];
        #pragma unroll
        for (int n = 0; n < 4; n++)
            bf_[n] = *(const short8*)&Bs[buf][(wid * 64 + n * 16 + fr) * BK + ph * 8];
        #pragma unroll
        for (int m = 0; m < 8; m++)
            #pragma unroll
            for (int n = 0; n < 4; n++)
                acc[m][n] = __builtin_amdgcn_mfma_f32_16x16x32_bf16(
                    af[m], bf_[n], acc[m][n], 0, 0, 0);
        buf ^= 1;
    }

    // epilogue (C/D: col=lane&15, row=(lane>>4)*4+j); bias folded:
    // out_row = s * (acc + b[e]); pure store (rank-1 RMW only in fallback)
    const bool rank1 = (li >= 8);
    float* dstBase = (rank1 && out2 != nullptr) ? out2 : out;
    const bool rmw = rank1 && (out2 == nullptr);
    const float* brow = bias + (size_t)exp_ * ODIM + n0 + wid * 64 + fr;
    float bv[4];
    #pragma unroll
    for (int n = 0; n < 4; n++) bv[n] = brow[n * 16];

    #pragma unroll
    for (int m = 0; m < 8; m++) {
        #pragma unroll
        for (int j = 0; j < 4; j++) {
            int r = m * 16 + g4 * 4 + j;
            int gr = m0 + r;
            if (gr < cnt) {
                int entry = list[gr];
                float s = scores2[entry];
                float* orow = dstBase + (size_t)(entry >> 1) * ODIM + n0 + wid * 64 + fr;
                if (rmw) {
                    #pragma unroll
                    for (int n = 0; n < 4; n++)
                        orow[n * 16] += s * (acc[m][n][j] + bv[n]);
                } else {
                    #pragma unroll
                    for (int n = 0; n < 4; n++)
                        orow[n * 16] = s * (acc[m][n][j] + bv[n]);
                }
            }
        }
    }
}

__global__ void k_add(float4* __restrict__ out, const float4* __restrict__ out2, int n4) {
    int i = blockIdx.x * blockDim.x + threadIdx.x;
    const int stride = gridDim.x * blockDim.x;
    #pragma unroll 1
    for (; i < n4; i += stride) {
        float4 a = out[i], c = out2[i];
        a.x += c.x; a.y += c.y; a.z += c.z; a.w += c.w;
        out[i] = a;
    }
}

extern "C" void kernel_launch(void* const* d_in, const int* in_sizes, int n_in,
                              void* d_out, int out_size, void* d_ws, size_t ws_size,
                              hipStream_t stream) {
    const float* x  = (const float*)d_in[0];
    const float* W  = (const float*)d_in[1];
    const float* b  = (const float*)d_in[2];
    const float* Wg = (const float*)d_in[3];
    const float* bg = (const float*)d_in[4];
    float* out = (float*)d_out;
    char* ws = (char*)d_ws;

    int*   counts  = (int*)(ws + CNT_OFF);    // [16]: rank0 experts, rank1 experts
    float* scores2 = (float*)(ws + SC_OFF);
    int*   lists   = (int*)(ws + LIST_OFF);   // [16][NTOK]
    unsigned short* xh = (unsigned short*)(ws + XH_OFF);
    unsigned short* wh = (unsigned short*)(ws + WH_OFF);
    float* out2 = (float*)(ws + O2_OFF);

    int n4w = NEXP * ODIM * DDIM / 4;
    k_cvtw<<<n4w / 256, 256, 0, stream>>>((const float4*)W, (ushort4*)wh, n4w, counts);

    k_gate<<<NTOK / 8, 256, 0, stream>>>(x, Wg, bg, scores2, lists, counts, xh);

    // block-per-tile: worst case sum_16 ceil(c/128)*4 <= (128+16)*4 = 576;
    // grid 576 (%8==0), 48KB LDS + ~210 VGPR -> 2 blocks/CU co-resident.
    if (ws_size >= WS_NEED) {
        k_gemm<<<576, 256, 0, stream>>>(xh, wh, counts, lists, scores2, b, out, out2, 0, 16);
        k_add<<<2048, 256, 0, stream>>>((float4*)out, (const float4*)out2, NTOK * ODIM / 4);
    } else {
        k_gemm<<<576, 256, 0, stream>>>(xh, wh, counts, lists, scores2, b, out, nullptr, 0, 8);
        k_gemm<<<576, 256, 0, stream>>>(xh, wh, counts, lists, scores2, b, out, nullptr, 8, 16);
    }
}

// Round 10
// 174.377 us; speedup vs baseline: 1.0841x; 1.0841x over previous
//
#include <hip/hip_runtime.h>
#include <hip/hip_bf16.h>

// Problem constants (B=4, S=2048 -> 8192 tokens; D=O=1024; E=8; top-2)
#define NTOK 8192
#define DDIM 1024
#define ODIM 1024
#define NEXP 8
#define BM   256
#define BN   256
#define BK   32
#define NKT  (DDIM / BK)     // 32 K-tiles

typedef __attribute__((ext_vector_type(8))) short short8;
typedef __attribute__((ext_vector_type(4))) float f32x4;

// ---- workspace layout (bytes) ----
#define CNT_OFF   0u                               // 16 ints (expert x rank)
#define SC_OFF    (4u * 1024u)                     // 8192*2 floats
#define LIST_OFF  (128u * 1024u)                   // 16*8192 ints = 512 KiB
#define XH_OFF    (1u << 20)                       // bf16 x, 16 MiB
#define WH_OFF    ((1u << 20) + 16u*1024u*1024u)   // bf16 W, 16 MiB
#define O2_OFF    ((1u << 20) + 32u*1024u*1024u)   // rank-1 accum, 32 MiB
#define WS_NEED   ((size_t)O2_OFF + (size_t)NTOK * ODIM * 4u)

__device__ inline unsigned short f2bf(float f) {
    unsigned int u = __float_as_uint(f);
    unsigned int r = (u + 0x7FFFu + ((u >> 16) & 1u)) >> 16;   // RNE
    return (unsigned short)r;
}

__device__ inline void glds16(const unsigned short* g, unsigned short* l) {
    __builtin_amdgcn_global_load_lds(
        (const __attribute__((address_space(1))) unsigned int*)g,
        (__attribute__((address_space(3))) unsigned int*)l, 16, 0, 0);
}

// W fp32->bf16; block 0 also zeroes the 16 expert-x-rank counts (pre-gate)
__global__ void k_cvtw(const float4* __restrict__ src, ushort4* __restrict__ dst,
                       int n4, int* __restrict__ counts) {
    if (blockIdx.x == 0 && threadIdx.x < 16) counts[threadIdx.x] = 0;
    int i = blockIdx.x * blockDim.x + threadIdx.x;
    if (i >= n4) return;
    float4 v = src[i];
    ushort4 o;
    o.x = f2bf(v.x); o.y = f2bf(v.y); o.z = f2bf(v.z); o.w = f2bf(v.w);
    dst[i] = o;
}

// Gating (round-6 proven form): 1024 blocks x 8 tokens (2 per wave). No VGPR
// clamp (round-5 spill lesson). fp64 dot+butterfly decides top-k; fp32 expf
// weights. 16 lists (expert x rank), block-aggregated scatter. Fused bf16
// conversion of x. Bias is folded into the GEMM epilogue.
__global__ __launch_bounds__(256) void k_gate(
    const float* __restrict__ x, const float* __restrict__ Wg,
    const float* __restrict__ bg, float* __restrict__ scores2,
    int* __restrict__ lists, int* __restrict__ counts,
    unsigned short* __restrict__ xh)
{
    __shared__ unsigned char s_eid[16];     // 8 tokens * 2 entries
    const int tid = threadIdx.x, wave = tid >> 6, lane = tid & 63;
    const int tblk = blockIdx.x * 8;

    #pragma unroll 1
    for (int ti = 0; ti < 2; ti++) {
        const int t = tblk + wave * 2 + ti;
        const float* xr = x + (size_t)t * DDIM;
        float4 xv[4];
        #pragma unroll
        for (int i = 0; i < 4; i++)
            xv[i] = *(const float4*)&xr[lane * 4 + 256 * i];

        unsigned short* xhr = xh + (size_t)t * DDIM;
        #pragma unroll
        for (int i = 0; i < 4; i++) {
            ushort4 h;
            h.x = f2bf(xv[i].x); h.y = f2bf(xv[i].y);
            h.z = f2bf(xv[i].z); h.w = f2bf(xv[i].w);
            *(ushort4*)&xhr[lane * 4 + 256 * i] = h;
        }

        double lg[NEXP];
        #pragma unroll
        for (int e = 0; e < NEXP; e++) {
            const float* wr = Wg + (size_t)e * DDIM;
            double a = 0.0;
            #pragma unroll
            for (int i = 0; i < 4; i++) {
                float4 wv = *(const float4*)&wr[lane * 4 + 256 * i];
                a += (double)xv[i].x * (double)wv.x + (double)xv[i].y * (double)wv.y
                   + (double)xv[i].z * (double)wv.z + (double)xv[i].w * (double)wv.w;
            }
            #pragma unroll
            for (int off = 32; off > 0; off >>= 1) a += __shfl_xor(a, off);
            lg[e] = a + (double)bg[e];
        }

        int i0 = -1, i1 = -1;
        double best = -1e300, sec = -1e300;
        #pragma unroll
        for (int e = 0; e < NEXP; e++) {
            double v = lg[e];
            if (v > best) { sec = best; i1 = i0; best = v; i0 = e; }
            else if (v > sec) { sec = v; i1 = e; }
        }
        float sum = 0.f;
        #pragma unroll
        for (int e = 0; e < NEXP; e++) sum += expf((float)(lg[e] - best));
        float s0 = 1.f / sum;
        float s1 = expf((float)(sec - best)) / sum;

        if (lane == 0) {
            scores2[t * 2 + 0] = s0;
            scores2[t * 2 + 1] = s1;
            int le = (wave * 2 + ti) * 2;
            s_eid[le + 0] = (unsigned char)i0;
            s_eid[le + 1] = (unsigned char)i1;
        }
    }
    __syncthreads();

    // 16 owners: e = tid&7, rank = tid>>3; one global atomic per (block,owner)
    if (tid < 16) {
        int e = tid & 7, kk = tid >> 3;
        int c = 0;
        #pragma unroll
        for (int j = 0; j < 8; j++) c += (s_eid[j * 2 + kk] == e);
        if (c) {
            int p = atomicAdd(&counts[tid], c);
            #pragma unroll
            for (int j = 0; j < 8; j++)
                if (s_eid[j * 2 + kk] == e)
                    lists[tid * NTOK + (p++)] = (tblk + j) * 2 + kk;
        }
    }
}

// Grouped GEMM, 256x256 tile (8 waves = 2M x 4N, wave-tile 128x64), BK=32,
// double-buffered 64 KiB static LDS, one __syncthreads per K-step (proven
// r6 sync). Tile-area amortization: LDS bytes/FLOP and barrier-drains/FLOP
// both halve vs 128x128. Full 8-spread XOR swizzle on 64B rows:
//   data(logical r, seg c) at phys_byte = (r*64 + c*16) ^ ((r&7)<<4)
// (bit6 of the mask folds row-bit0; involution applied on BOTH stage-src and
// read addresses -> 16-lane column reads hit all 8 16B-slots = 2-way = free).
// Epilogue: bias folded, pure stores (rank-0 -> out, rank-1 -> out2).
__global__ __launch_bounds__(512, 2) void k_gemm(
    const unsigned short* __restrict__ xh, const unsigned short* __restrict__ wh,
    const int* __restrict__ counts, const int* __restrict__ lists,
    const float* __restrict__ scores2, const float* __restrict__ bias,
    float* __restrict__ out, float* __restrict__ out2, int listLo, int listHi)
{
    __shared__ __align__(16) unsigned short As[2][BM * BK];   // 32 KiB
    __shared__ __align__(16) unsigned short Bs[2][BN * BK];   // 32 KiB

    // bijective chunked XCD swizzle (gridDim % 8 == 0)
    const int nwg = (int)gridDim.x;
    int bid = ((int)blockIdx.x & 7) * (nwg >> 3) + ((int)blockIdx.x >> 3);

    int li = -1, mt = 0, nt = 0, cnt = 0;
    #pragma unroll
    for (int i = 0; i < 16; i++) {
        if (i < listLo || i >= listHi) continue;
        int c = counts[i];
        int tiles = ((c + 255) >> 8) * 4;      // 4 n-tiles (BN=256)
        if (li < 0) {
            if (bid < tiles) { li = i; mt = bid >> 2; nt = bid & 3; cnt = c; }
            else bid -= tiles;
        }
    }
    if (li < 0) return;

    const int m0 = mt * 256, n0 = nt * 256;
    const int* list = lists + li * NTOK;
    const int exp_ = li & 7;
    const unsigned short* whE = wh + (size_t)exp_ * ODIM * DDIM;
    const int tid = threadIdx.x, wid = tid >> 6, lane = tid & 63;

    // ---- staging: per wave 2 A-instrs + 2 B-instrs, each 1KB = 16 phys rows.
    // dest lane layout: phys row P = base + (lane>>2), phys seg s = lane&3.
    // inverse swizzle for the global source: logical r = P ^ ((P>>2)&1),
    // logical seg c = s ^ (r&3).
    const unsigned short* aS[2];
    const unsigned short* bS[2];
    unsigned short* aD[2];
    unsigned short* bD[2];
    #pragma unroll
    for (int i = 0; i < 2; i++) {
        const int base = (wid * 2 + i) * 16;
        const int P = base + (lane >> 2), s = lane & 3;
        const int r = P ^ ((P >> 2) & 1);
        const int c = s ^ (r & 3);
        int g = m0 + r; if (g >= cnt) g = cnt - 1;
        aS[i] = xh + (size_t)(list[g] >> 1) * DDIM + c * 8;
        bS[i] = whE + (size_t)(n0 + r) * DDIM + c * 8;
        aD[i] = &As[0][(wid * 2 + i) * 512];    // wave-uniform dest base
        bD[i] = &Bs[0][(wid * 2 + i) * 512];
    }

    // ---- fragment read byte-offsets (swizzled) ----
    const int wm = wid >> 2, wn = wid & 3;      // 2M x 4N wave grid
    const int fr = lane & 15, g4 = lane >> 4;
    int offA[8], offB[4];
    #pragma unroll
    for (int m = 0; m < 8; m++) {
        int R = wm * 128 + m * 16 + fr;
        offA[m] = (R * 64 + g4 * 16) ^ ((R & 7) << 4);
    }
    #pragma unroll
    for (int n = 0; n < 4; n++) {
        int R = wn * 64 + n * 16 + fr;
        offB[n] = (R * 64 + g4 * 16) ^ ((R & 7) << 4);
    }

    f32x4 acc[8][4];
    #pragma unroll
    for (int m = 0; m < 8; m++)
        #pragma unroll
        for (int n = 0; n < 4; n++)
            acc[m][n] = (f32x4){0.f, 0.f, 0.f, 0.f};

    // prologue: stage K-tile 0 into buf 0
    #pragma unroll
    for (int i = 0; i < 2; i++) {
        glds16(aS[i], aD[i]);
        glds16(bS[i], bD[i]);
    }

    int buf = 0;
    #pragma unroll 1
    for (int t = 0; t < NKT; t++) {
        __syncthreads();                 // stage(t) landed (vmcnt drain)
        if (t + 1 < NKT) {
            const int k0 = (t + 1) * BK;
            const int od = (buf ^ 1) * (BM * BK);
            #pragma unroll
            for (int i = 0; i < 2; i++) {
                glds16(aS[i] + k0, aD[i] + od);
                glds16(bS[i] + k0, bD[i] + od);
            }
        }
        const char* ab = (const char*)&As[buf][0];
        const char* bb = (const char*)&Bs[buf][0];
        short8 af[8], bfv[4];
        #pragma unroll
        for (int m = 0; m < 8; m++) af[m] = *(const short8*)(ab + offA[m]);
        #pragma unroll
        for (int n = 0; n < 4; n++) bfv[n] = *(const short8*)(bb + offB[n]);
        #pragma unroll
        for (int m = 0; m < 8; m++)
            #pragma unroll
            for (int n = 0; n < 4; n++)
                acc[m][n] = __builtin_amdgcn_mfma_f32_16x16x32_bf16(
                    af[m], bfv[n], acc[m][n], 0, 0, 0);
        buf ^= 1;
    }

    // epilogue (C/D: col=lane&15, row=(lane>>4)*4+j); bias folded:
    // out_row = s * (acc + b[e]); pure store (rank-1 RMW only in fallback)
    const bool rank1 = (li >= 8);
    float* dstBase = (rank1 && out2 != nullptr) ? out2 : out;
    const bool rmw = rank1 && (out2 == nullptr);
    const float* brow = bias + (size_t)exp_ * ODIM + n0 + wn * 64 + fr;
    float bv[4];
    #pragma unroll
    for (int n = 0; n < 4; n++) bv[n] = brow[n * 16];

    #pragma unroll
    for (int m = 0; m < 8; m++) {
        #pragma unroll
        for (int j = 0; j < 4; j++) {
            int r = wm * 128 + m * 16 + g4 * 4 + j;
            int gr = m0 + r;
            if (gr < cnt) {
                int entry = list[gr];
                float s = scores2[entry];
                float* orow = dstBase + (size_t)(entry >> 1) * ODIM + n0 + wn * 64 + fr;
                if (rmw) {
                    #pragma unroll
                    for (int n = 0; n < 4; n++)
                        orow[n * 16] += s * (acc[m][n][j] + bv[n]);
                } else {
                    #pragma unroll
                    for (int n = 0; n < 4; n++)
                        orow[n * 16] = s * (acc[m][n][j] + bv[n]);
                }
            }
        }
    }
}

__global__ void k_add(float4* __restrict__ out, const float4* __restrict__ out2, int n4) {
    int i = blockIdx.x * blockDim.x + threadIdx.x;
    const int stride = gridDim.x * blockDim.x;
    #pragma unroll 1
    for (; i < n4; i += stride) {
        float4 a = out[i], c = out2[i];
        a.x += c.x; a.y += c.y; a.z += c.z; a.w += c.w;
        out[i] = a;
    }
}

extern "C" void kernel_launch(void* const* d_in, const int* in_sizes, int n_in,
                              void* d_out, int out_size, void* d_ws, size_t ws_size,
                              hipStream_t stream) {
    const float* x  = (const float*)d_in[0];
    const float* W  = (const float*)d_in[1];
    const float* b  = (const float*)d_in[2];
    const float* Wg = (const float*)d_in[3];
    const float* bg = (const float*)d_in[4];
    float* out = (float*)d_out;
    char* ws = (char*)d_ws;

    int*   counts  = (int*)(ws + CNT_OFF);    // [16]: rank0 experts, rank1 experts
    float* scores2 = (float*)(ws + SC_OFF);
    int*   lists   = (int*)(ws + LIST_OFF);   // [16][NTOK]
    unsigned short* xh = (unsigned short*)(ws + XH_OFF);
    unsigned short* wh = (unsigned short*)(ws + WH_OFF);
    float* out2 = (float*)(ws + O2_OFF);

    int n4w = NEXP * ODIM * DDIM / 4;
    k_cvtw<<<n4w / 256, 256, 0, stream>>>((const float4*)W, (ushort4*)wh, n4w, counts);

    k_gate<<<NTOK / 8, 256, 0, stream>>>(x, Wg, bg, scores2, lists, counts, xh);

    // block-per-tile: worst case sum_16 ceil(c/256)*4 <= (32+7)*4*2 = 312;
    // grid 320 (%8==0). 64KB LDS + ~210 VGPR -> 1 block/CU, 8 waves.
    if (ws_size >= WS_NEED) {
        k_gemm<<<320, 512, 0, stream>>>(xh, wh, counts, lists, scores2, b, out, out2, 0, 16);
        k_add<<<2048, 256, 0, stream>>>((float4*)out, (const float4*)out2, NTOK * ODIM / 4);
    } else {
        k_gemm<<<320, 512, 0, stream>>>(xh, wh, counts, lists, scores2, b, out, nullptr, 0, 8);
        k_gemm<<<320, 512, 0, stream>>>(xh, wh, counts, lists, scores2, b, out, nullptr, 8, 16);
    }
}

// Round 11
// 146.741 us; speedup vs baseline: 1.2883x; 1.1883x over previous
//
#include <hip/hip_runtime.h>
#include <hip/hip_bf16.h>

// Problem constants (B=4, S=2048 -> 8192 tokens; D=O=1024; E=8; top-2)
#define NTOK 8192
#define DDIM 1024
#define ODIM 1024
#define NEXP 8
#define BK   64
#define NKT  (DDIM / BK)     // 16 K-tiles

typedef __attribute__((ext_vector_type(8))) short short8;
typedef __attribute__((ext_vector_type(4))) float f32x4;

// ---- workspace layout (bytes) ----
#define CNT_OFF   0u                               // 16 ints (expert x rank)
#define SC_OFF    (4u * 1024u)                     // 8192*2 floats
#define LIST_OFF  (128u * 1024u)                   // 16*8192 ints = 512 KiB
#define XH_OFF    (1u << 20)                       // bf16 x, 16 MiB
#define WH_OFF    ((1u << 20) + 16u*1024u*1024u)   // bf16 W, 16 MiB
#define O2_OFF    ((1u << 20) + 32u*1024u*1024u)   // rank-1 accum, 32 MiB
#define WS_NEED   ((size_t)O2_OFF + (size_t)NTOK * ODIM * 4u)

__device__ inline unsigned short f2bf(float f) {
    unsigned int u = __float_as_uint(f);
    unsigned int r = (u + 0x7FFFu + ((u >> 16) & 1u)) >> 16;   // RNE
    return (unsigned short)r;
}

__device__ inline void glds16(const unsigned short* g, unsigned short* l) {
    __builtin_amdgcn_global_load_lds(
        (const __attribute__((address_space(1))) unsigned int*)g,
        (__attribute__((address_space(3))) unsigned int*)l, 16, 0, 0);
}

// W fp32->bf16; block 0 also zeroes the 16 expert-x-rank counts (pre-gate)
__global__ void k_cvtw(const float4* __restrict__ src, ushort4* __restrict__ dst,
                       int n4, int* __restrict__ counts) {
    if (blockIdx.x == 0 && threadIdx.x < 16) counts[threadIdx.x] = 0;
    int i = blockIdx.x * blockDim.x + threadIdx.x;
    if (i >= n4) return;
    float4 v = src[i];
    ushort4 o;
    o.x = f2bf(v.x); o.y = f2bf(v.y); o.z = f2bf(v.z); o.w = f2bf(v.w);
    dst[i] = o;
}

// Gating (round-6 proven form): 1024 blocks x 8 tokens (2 per wave). No VGPR
// clamp (round-5 spill lesson). fp64 dot+butterfly decides top-k; fp32 expf
// weights. 16 lists (expert x rank), block-aggregated scatter. Fused bf16
// conversion of x. Bias is folded into the GEMM epilogue.
__global__ __launch_bounds__(256) void k_gate(
    const float* __restrict__ x, const float* __restrict__ Wg,
    const float* __restrict__ bg, float* __restrict__ scores2,
    int* __restrict__ lists, int* __restrict__ counts,
    unsigned short* __restrict__ xh)
{
    __shared__ unsigned char s_eid[16];     // 8 tokens * 2 entries
    const int tid = threadIdx.x, wave = tid >> 6, lane = tid & 63;
    const int tblk = blockIdx.x * 8;

    #pragma unroll 1
    for (int ti = 0; ti < 2; ti++) {
        const int t = tblk + wave * 2 + ti;
        const float* xr = x + (size_t)t * DDIM;
        float4 xv[4];
        #pragma unroll
        for (int i = 0; i < 4; i++)
            xv[i] = *(const float4*)&xr[lane * 4 + 256 * i];

        unsigned short* xhr = xh + (size_t)t * DDIM;
        #pragma unroll
        for (int i = 0; i < 4; i++) {
            ushort4 h;
            h.x = f2bf(xv[i].x); h.y = f2bf(xv[i].y);
            h.z = f2bf(xv[i].z); h.w = f2bf(xv[i].w);
            *(ushort4*)&xhr[lane * 4 + 256 * i] = h;
        }

        double lg[NEXP];
        #pragma unroll
        for (int e = 0; e < NEXP; e++) {
            const float* wr = Wg + (size_t)e * DDIM;
            double a = 0.0;
            #pragma unroll
            for (int i = 0; i < 4; i++) {
                float4 wv = *(const float4*)&wr[lane * 4 + 256 * i];
                a += (double)xv[i].x * (double)wv.x + (double)xv[i].y * (double)wv.y
                   + (double)xv[i].z * (double)wv.z + (double)xv[i].w * (double)wv.w;
            }
            #pragma unroll
            for (int off = 32; off > 0; off >>= 1) a += __shfl_xor(a, off);
            lg[e] = a + (double)bg[e];
        }

        int i0 = -1, i1 = -1;
        double best = -1e300, sec = -1e300;
        #pragma unroll
        for (int e = 0; e < NEXP; e++) {
            double v = lg[e];
            if (v > best) { sec = best; i1 = i0; best = v; i0 = e; }
            else if (v > sec) { sec = v; i1 = e; }
        }
        float sum = 0.f;
        #pragma unroll
        for (int e = 0; e < NEXP; e++) sum += expf((float)(lg[e] - best));
        float s0 = 1.f / sum;
        float s1 = expf((float)(sec - best)) / sum;

        if (lane == 0) {
            scores2[t * 2 + 0] = s0;
            scores2[t * 2 + 1] = s1;
            int le = (wave * 2 + ti) * 2;
            s_eid[le + 0] = (unsigned char)i0;
            s_eid[le + 1] = (unsigned char)i1;
        }
    }
    __syncthreads();

    // 16 owners: e = tid&7, rank = tid>>3; one global atomic per (block,owner)
    if (tid < 16) {
        int e = tid & 7, kk = tid >> 3;
        int c = 0;
        #pragma unroll
        for (int j = 0; j < 8; j++) c += (s_eid[j * 2 + kk] == e);
        if (c) {
            int p = atomicAdd(&counts[tid], c);
            #pragma unroll
            for (int j = 0; j < 8; j++)
                if (s_eid[j * 2 + kk] == e)
                    lists[tid * NTOK + (p++)] = (tblk + j) * 2 + kk;
        }
    }
}

// Grouped GEMM over 16 (expert x rank) lists, BLOCK-PER-TILE. 128x128 tile,
// BK=64 (16 K-steps: half the barrier/vmcnt-drain events of r6's BK=32 --
// the drain bubble is per-step and latency-driven), double-buffered 64 KiB
// LDS -> 2 blocks/CU co-resident (bubble overlap across blocks, the r6
// property that r9/r10 lost). Sync skeleton IDENTICAL to round 6 (proven):
// one __syncthreads per K-step; stage(t+1) issued right after it.
// Swizzle (128B rows, bits 4-6 = slot index -> pure within-row involution):
//   phys_byte = logical_byte ^ ((row&7)<<4)
// applied on BOTH the glds global source (inverse) and the ds_read offsets.
// Epilogue: bias folded, pure stores (rank-0 -> out, rank-1 -> out2).
__global__ __launch_bounds__(256) void k_gemm(
    const unsigned short* __restrict__ xh, const unsigned short* __restrict__ wh,
    const int* __restrict__ counts, const int* __restrict__ lists,
    const float* __restrict__ scores2, const float* __restrict__ bias,
    float* __restrict__ out, float* __restrict__ out2, int listLo, int listHi)
{
    __shared__ __align__(16) unsigned short As[2][128 * BK];   // 32 KiB
    __shared__ __align__(16) unsigned short Bs[2][128 * BK];   // 32 KiB

    // bijective chunked XCD swizzle (gridDim % 8 == 0)
    const int nwg = (int)gridDim.x;
    int bid = ((int)blockIdx.x & 7) * (nwg >> 3) + ((int)blockIdx.x >> 3);

    int li = -1, mt = 0, nt = 0, cnt = 0;
    #pragma unroll
    for (int i = 0; i < 16; i++) {
        if (i < listLo || i >= listHi) continue;
        int c = counts[i];
        int tiles = ((c + 127) >> 7) * 8;      // 8 n-tiles (BN=128)
        if (li < 0) {
            if (bid < tiles) { li = i; mt = bid >> 3; nt = bid & 7; cnt = c; }
            else bid -= tiles;
        }
    }
    if (li < 0) return;

    const int m0 = mt * 128, n0 = nt * 128;
    const int* list = lists + li * NTOK;
    const int exp_ = li & 7;
    const unsigned short* whE = wh + (size_t)exp_ * ODIM * DDIM;
    const int tid = threadIdx.x, wid = tid >> 6, lane = tid & 63;

    // ---- staging: per thread 4 A + 4 B glds per K-step; instr i covers
    // phys rows [(wid*4+i)*8, +8). Lane -> row P = base + (lane>>3),
    // slot s = lane&7. Inverse swizzle: logical row = P, logical slot
    // c = s ^ (P&7) -> global col = c*8 elems.
    const int l8 = lane >> 3, s8 = lane & 7;
    const unsigned short* aS[4];
    const unsigned short* bS[4];
    int rbase[4];
    #pragma unroll
    for (int i = 0; i < 4; i++) {
        const int rb = (wid * 4 + i) * 8;
        rbase[i] = rb;
        const int P = rb + l8;
        const int c = s8 ^ (P & 7);
        int g = m0 + P; if (g >= cnt) g = cnt - 1;
        aS[i] = xh + (size_t)(list[g] >> 1) * DDIM + c * 8;
        bS[i] = whE + (size_t)(n0 + P) * DDIM + c * 8;
    }

    // ---- fragment read byte-offsets (swizzled) ----
    const int wm = wid >> 1, wn = wid & 1;      // 2x2 wave grid, wave-tile 64x64
    const int fr = lane & 15, g4 = lane >> 4;
    int offA[4][2], offB[4][2];
    #pragma unroll
    for (int m = 0; m < 4; m++) {
        int R = wm * 64 + m * 16 + fr;
        #pragma unroll
        for (int kk = 0; kk < 2; kk++)
            offA[m][kk] = (R * 128 + kk * 64 + g4 * 16) ^ ((R & 7) << 4);
    }
    #pragma unroll
    for (int n = 0; n < 4; n++) {
        int R = wn * 64 + n * 16 + fr;
        #pragma unroll
        for (int kk = 0; kk < 2; kk++)
            offB[n][kk] = (R * 128 + kk * 64 + g4 * 16) ^ ((R & 7) << 4);
    }

    f32x4 acc[4][4];
    #pragma unroll
    for (int m = 0; m < 4; m++)
        #pragma unroll
        for (int n = 0; n < 4; n++)
            acc[m][n] = (f32x4){0.f, 0.f, 0.f, 0.f};

    // prologue: stage K-tile 0 into buf 0
    #pragma unroll
    for (int i = 0; i < 4; i++) {
        glds16(aS[i], &As[0][rbase[i] * BK]);
        glds16(bS[i], &Bs[0][rbase[i] * BK]);
    }

    int buf = 0;
    #pragma unroll 1
    for (int t = 0; t < NKT; t++) {
        __syncthreads();                 // stage(t) landed (vmcnt drain)
        if (t + 1 < NKT) {
            const int k0 = (t + 1) * BK;
            #pragma unroll
            for (int i = 0; i < 4; i++) {
                glds16(aS[i] + k0, &As[buf ^ 1][rbase[i] * BK]);
                glds16(bS[i] + k0, &Bs[buf ^ 1][rbase[i] * BK]);
            }
        }
        const char* ab = (const char*)&As[buf][0];
        const char* bb = (const char*)&Bs[buf][0];
        short8 af[4][2], bfv[4][2];
        #pragma unroll
        for (int m = 0; m < 4; m++) {
            af[m][0] = *(const short8*)(ab + offA[m][0]);
            af[m][1] = *(const short8*)(ab + offA[m][1]);
        }
        #pragma unroll
        for (int n = 0; n < 4; n++) {
            bfv[n][0] = *(const short8*)(bb + offB[n][0]);
            bfv[n][1] = *(const short8*)(bb + offB[n][1]);
        }
        #pragma unroll
        for (int kk = 0; kk < 2; kk++)
            #pragma unroll
            for (int m = 0; m < 4; m++)
                #pragma unroll
                for (int n = 0; n < 4; n++)
                    acc[m][n] = __builtin_amdgcn_mfma_f32_16x16x32_bf16(
                        af[m][kk], bfv[n][kk], acc[m][n], 0, 0, 0);
        buf ^= 1;
    }

    // epilogue (C/D: col=lane&15, row=(lane>>4)*4+j); bias folded:
    // out_row = s * (acc + b[e]); pure store (rank-1 RMW only in fallback)
    const bool rank1 = (li >= 8);
    float* dstBase = (rank1 && out2 != nullptr) ? out2 : out;
    const bool rmw = rank1 && (out2 == nullptr);
    const float* brow = bias + (size_t)exp_ * ODIM + n0 + wn * 64 + fr;
    float bv[4];
    #pragma unroll
    for (int n = 0; n < 4; n++) bv[n] = brow[n * 16];

    #pragma unroll
    for (int m = 0; m < 4; m++) {
        #pragma unroll
        for (int j = 0; j < 4; j++) {
            int r = wm * 64 + m * 16 + g4 * 4 + j;
            int gr = m0 + r;
            if (gr < cnt) {
                int entry = list[gr];
                float s = scores2[entry];
                float* orow = dstBase + (size_t)(entry >> 1) * ODIM + n0 + wn * 64 + fr;
                if (rmw) {
                    #pragma unroll
                    for (int n = 0; n < 4; n++)
                        orow[n * 16] += s * (acc[m][n][j] + bv[n]);
                } else {
                    #pragma unroll
                    for (int n = 0; n < 4; n++)
                        orow[n * 16] = s * (acc[m][n][j] + bv[n]);
                }
            }
        }
    }
}

__global__ void k_add(float4* __restrict__ out, const float4* __restrict__ out2, int n4) {
    int i = blockIdx.x * blockDim.x + threadIdx.x;
    const int stride = gridDim.x * blockDim.x;
    #pragma unroll 1
    for (; i < n4; i += stride) {
        float4 a = out[i], c = out2[i];
        a.x += c.x; a.y += c.y; a.z += c.z; a.w += c.w;
        out[i] = a;
    }
}

extern "C" void kernel_launch(void* const* d_in, const int* in_sizes, int n_in,
                              void* d_out, int out_size, void* d_ws, size_t ws_size,
                              hipStream_t stream) {
    const float* x  = (const float*)d_in[0];
    const float* W  = (const float*)d_in[1];
    const float* b  = (const float*)d_in[2];
    const float* Wg = (const float*)d_in[3];
    const float* bg = (const float*)d_in[4];
    float* out = (float*)d_out;
    char* ws = (char*)d_ws;

    int*   counts  = (int*)(ws + CNT_OFF);    // [16]: rank0 experts, rank1 experts
    float* scores2 = (float*)(ws + SC_OFF);
    int*   lists   = (int*)(ws + LIST_OFF);   // [16][NTOK]
    unsigned short* xh = (unsigned short*)(ws + XH_OFF);
    unsigned short* wh = (unsigned short*)(ws + WH_OFF);
    float* out2 = (float*)(ws + O2_OFF);

    int n4w = NEXP * ODIM * DDIM / 4;
    k_cvtw<<<n4w / 256, 256, 0, stream>>>((const float4*)W, (ushort4*)wh, n4w, counts);

    k_gate<<<NTOK / 8, 256, 0, stream>>>(x, Wg, bg, scores2, lists, counts, xh);

    // block-per-tile: worst case sum_16 ceil(c/128)*8 <= (128+16)*8 = 1152;
    // grid 1152 (%8==0). 64KB LDS -> 2 blocks/CU co-resident.
    if (ws_size >= WS_NEED) {
        k_gemm<<<1152, 256, 0, stream>>>(xh, wh, counts, lists, scores2, b, out, out2, 0, 16);
        k_add<<<2048, 256, 0, stream>>>((float4*)out, (const float4*)out2, NTOK * ODIM / 4);
    } else {
        k_gemm<<<1152, 256, 0, stream>>>(xh, wh, counts, lists, scores2, b, out, nullptr, 0, 8);
        k_gemm<<<1152, 256, 0, stream>>>(xh, wh, counts, lists, scores2, b, out, nullptr, 8, 16);
    }
}